// Round 1
// baseline (84.491 us; speedup 1.0000x reference)
//
#include <hip/hip_runtime.h>

// Round 8: fuse everything into ONE kernel (plus a 1 KB counter memset).
//   - gram partials unchanged (proven core from r4, 81 µs config)
//   - k-slice reduce re-laid-out: old smem[(s*16+tile)*16+e] had bank =
//     (tile*16+e)%32 -> 64 lanes on 2 banks = 32-way conflict x16 stores.
//     New layout smem[e*LDR + slot] with LDR=264 (mod 32 == 8): writes span
//     64 consecutive slots (2-way, free), reads are (8e+tt)%32 (<=2-way, free).
//   - last-of-8-chunks block finalizes its identity inline (counter per
//     identity); last-of-256-identities block writes out[0] directly.
//     Ordering: sc-flagged (agent-scope relaxed atomic) stores/loads for all
//     cross-block data + __syncthreads() vmcnt-drain before each counter bump.
//     No buffer_wbl2/inv fences needed, no spinning (no deadlock), fixed
//     reduction order (deterministic).
//   - removes finalize dispatch AND out-memset: 3 dispatches -> 2.

#define NN      4096
#define DD      2048
#define KK      8
#define HALF    (NN / 2)
#define ROWS    16
#define CHUNK   256
#define NCHUNK  (DD / CHUNK)        // 8
#define LDW     (CHUNK + 4)         // 260: staging stride (unchanged)
#define LDR     264                 // reduce stride; 264 % 32 == 8
#define NIDENT  (NN / (2 * KK))     // 256 identities
#define NBLK    (NIDENT * NCHUNK)   // 2048 blocks
#define GRAMF   (NBLK * 256)        // 524288 floats = 2 MB of ws

__launch_bounds__(256, 4)
__global__ void fused_kernel(const float* __restrict__ x,
                             float* __restrict__ ws,
                             float* __restrict__ out,
                             int out_n) {
    __shared__ float smem[16 * LDR];        // 16.9 KB: staging, reduce, final sum
    __shared__ float Gs[ROWS][ROWS + 1];
    __shared__ float norms[ROWS];
    __shared__ float cbuf[ROWS];
    __shared__ unsigned lastFlag;

    const int blk = blockIdx.x;             // 0..2047
    const int p   = blk >> 3;               // identity
    const int c   = blk & 7;                // D-chunk
    const int t   = threadIdx.x;            // 0..255

    // ---- stage 16 rows x 256 cols (4 float4/thread, coalesced) ----
    #pragma unroll
    for (int it = 0; it < 4; ++it) {
        const int q    = it * 256 + t;
        const int r    = q >> 6;
        const int c4   = q & 63;
        const int grow = (r < KK) ? (p * KK + r) : (HALF + p * KK + (r - KK));
        const float4 v = *(const float4*)(x + (size_t)grow * DD + c * CHUNK + c4 * 4);
        *(float4*)(&smem[r * LDW + c4 * 4]) = v;
    }
    __syncthreads();

    // ---- 4x4 register-tiled partial Gram (unchanged core) ----
    const int s    = t >> 4;                // k-slice 0..15
    const int tile = t & 15;
    const int ti   = tile >> 2;
    const int tj   = tile & 3;

    float acc[4][4];
    #pragma unroll
    for (int a = 0; a < 4; ++a)
        #pragma unroll
        for (int b = 0; b < 4; ++b) acc[a][b] = 0.0f;

    const float* __restrict__ ra = &smem[(4 * ti) * LDW];
    const float* __restrict__ rb = &smem[(4 * tj) * LDW];
    #pragma unroll
    for (int step = 0; step < 4; ++step) {
        const int col = 4 * (s + 16 * step);
        float4 av[4];
        #pragma unroll
        for (int r = 0; r < 4; ++r) av[r] = *(const float4*)(ra + r * LDW + col);
        #pragma unroll
        for (int br = 0; br < 4; ++br) {
            const float4 bv = *(const float4*)(rb + br * LDW + col);
            #pragma unroll
            for (int ar = 0; ar < 4; ++ar) {
                acc[ar][br] = fmaf(av[ar].x, bv.x, acc[ar][br]);
                acc[ar][br] = fmaf(av[ar].y, bv.y, acc[ar][br]);
                acc[ar][br] = fmaf(av[ar].z, bv.z, acc[ar][br]);
                acc[ar][br] = fmaf(av[ar].w, bv.w, acc[ar][br]);
            }
        }
    }

    // ---- k-slice reduce, conflict-free layout ----
    __syncthreads();
    #pragma unroll
    for (int ar = 0; ar < 4; ++ar)
        #pragma unroll
        for (int br = 0; br < 4; ++br)
            smem[(ar * 4 + br) * LDR + t] = acc[ar][br];   // lanes -> 64 consecutive slots
    __syncthreads();
    {
        const int e  = t >> 4;              // Gram entry 0..15 within 4x4 tile
        const int tt = t & 15;              // which 4x4 tile
        float g = 0.0f;
        #pragma unroll
        for (int ss = 0; ss < 16; ++ss) g += smem[e * LDR + ss * 16 + tt];
        const int gi = 4 * (tt >> 2) + (e >> 2);
        const int gj = 4 * (tt & 3) + (e & 3);
        __hip_atomic_store(&ws[(size_t)blk * 256 + gi * 16 + gj], g,
                           __ATOMIC_RELAXED, __HIP_MEMORY_SCOPE_AGENT);
    }

    float*    contrib = ws + GRAMF;                       // [256] floats
    unsigned* cnt     = (unsigned*)(ws + GRAMF + NIDENT); // [256] chunk counters
    unsigned* done    = cnt + NIDENT;                     // [1] identity counter

    // ---- chunk completion: 8th-arriving block finalizes identity p ----
    __syncthreads();    // vmcnt drain: sc-flagged gram stores globally visible
    if (t == 0) {
        unsigned old = __hip_atomic_fetch_add(&cnt[p], 1u,
                          __ATOMIC_RELAXED, __HIP_MEMORY_SCOPE_AGENT);
        lastFlag = (old == NCHUNK - 1);
    }
    __syncthreads();
    if (!lastFlag) return;

    float gsum = 0.0f;
    #pragma unroll
    for (int cc = 0; cc < NCHUNK; ++cc)
        gsum += __hip_atomic_load(&ws[((size_t)(p * NCHUNK + cc)) * 256 + t],
                                  __ATOMIC_RELAXED, __HIP_MEMORY_SCOPE_AGENT);

    const int i = t >> 4;
    const int j = t & 15;
    Gs[i][j] = gsum;
    if (i == j) norms[i] = sqrtf(gsum) + 1e-10f;
    __syncthreads();

    if (t < ROWS) {
        const float ni = norms[t];
        float mf = Gs[t][0] / (ni * norms[0]);
        #pragma unroll
        for (int jj = 1; jj < 8; ++jj) mf = fminf(mf, Gs[t][jj] / (ni * norms[jj]));
        float ms = Gs[t][8] / (ni * norms[8]);
        #pragma unroll
        for (int jj = 9; jj < 16; ++jj) ms = fminf(ms, Gs[t][jj] / (ni * norms[jj]));
        cbuf[t] = fmaxf(1.0f - mf, 0.0f) + fmaxf(1.0f - ms, 0.0f);
    }
    __syncthreads();
    if (t == 0) {
        float sum = 0.0f;
        #pragma unroll
        for (int r = 0; r < ROWS; ++r) sum += cbuf[r];
        __hip_atomic_store(&contrib[p], sum,
                           __ATOMIC_RELAXED, __HIP_MEMORY_SCOPE_AGENT);
    }

    // ---- identity completion: 256th finalizer writes the grand total ----
    __syncthreads();    // vmcnt drain: contrib store globally visible
    if (t == 0) {
        unsigned old = __hip_atomic_fetch_add(done, 1u,
                          __ATOMIC_RELAXED, __HIP_MEMORY_SCOPE_AGENT);
        lastFlag = (old == NIDENT - 1);
    }
    __syncthreads();
    if (!lastFlag) return;

    smem[t] = __hip_atomic_load(&contrib[t],
                                __ATOMIC_RELAXED, __HIP_MEMORY_SCOPE_AGENT);
    __syncthreads();
    if (t < 64) smem[t] = (smem[t] + smem[t + 64]) + (smem[t + 128] + smem[t + 192]);
    __syncthreads();
    if (t == 0) {
        float total = 0.0f;
        #pragma unroll
        for (int r = 0; r < 64; ++r) total += smem[r];
        out[0] = total;                       // replaces memset+atomicAdd
    }
    for (int o = t; o < out_n; o += 256)
        if (o > 0) out[o] = 0.0f;
}

extern "C" void kernel_launch(void* const* d_in, const int* in_sizes, int n_in,
                              void* d_out, int out_size, void* d_ws, size_t ws_size,
                              hipStream_t stream) {
    const float* x = (const float*)d_in[0];
    float* out = (float*)d_out;
    float* ws  = (float*)d_ws;   // 2 MB gram + 1 KB contrib + 1 KB counters
    // zero the 256 chunk counters + 1 done counter (1028 B, ws is re-poisoned
    // by the harness each iteration so this must run every call)
    hipMemsetAsync((char*)d_ws + (size_t)(GRAMF + NIDENT) * sizeof(float), 0,
                   (NIDENT + 1) * sizeof(unsigned), stream);
    fused_kernel<<<NBLK, 256, 0, stream>>>(x, ws, out, out_size);
}

// Round 2
// 83.366 us; speedup vs baseline: 1.0135x; 1.0135x over previous
//
#include <hip/hip_runtime.h>

// Round 9: revert round-8 fusion (84.5 µs — regression vs 82.6/81.0 split).
// Post-mortem of r8: fusion gains were already known to be sub-noise (r6);
// inlined finalize + agent-scope atomics added register pressure and
// cross-XCD (L2-bypassing) traffic. Back to the proven 3-dispatch structure.
// KEPT from r8: conflict-free k-slice reduce layout. Old layout
// smem[(s*16+tile)*16+e] had bank=(16*tile+e)%32 -> 64 lanes on 2 banks
// (32-way conflict) on 16 stores + 16 reads per thread. New layout
// smem[e*LDR+slot], LDR=264 (mod 32 == 8): writes span 64 consecutive
// slots (2-way, free), reads cover each bank exactly 2x per wave (free).

#define NN      4096
#define DD      2048
#define KK      8
#define HALF    (NN / 2)
#define ROWS    16
#define CHUNK   256
#define NCHUNK  (DD / CHUNK)   // 8
#define LDW     (CHUNK + 4)    // 260: staging stride (not a bank multiple)
#define LDR     264            // reduce stride; 264 % 32 == 8

__launch_bounds__(256, 4)
__global__ void gram_partial_kernel(const float* __restrict__ x,
                                    float* __restrict__ ws) {
    __shared__ float smem[16 * LDR];   // 16.9 KB (staging needs 16*260, reduce 16*264)

    const int blk = blockIdx.x;          // 0..2047
    const int p   = blk >> 3;            // identity
    const int c   = blk & 7;             // D-chunk
    const int t   = threadIdx.x;         // 0..255

    // Stage 16 rows x 256 cols (4 float4/thread, fully coalesced).
    #pragma unroll
    for (int it = 0; it < 4; ++it) {
        const int q    = it * 256 + t;   // 0..1023
        const int r    = q >> 6;         // local row 0..15 (64 float4 per row)
        const int c4   = q & 63;
        const int grow = (r < KK) ? (p * KK + r) : (HALF + p * KK + (r - KK));
        const float4 v = *(const float4*)(x + (size_t)grow * DD + c * CHUNK + c4 * 4);
        *(float4*)(&smem[r * LDW + c4 * 4]) = v;
    }
    __syncthreads();

    // 4x4 register-tiled partial Gram. thread t = (kslice s, tile).
    const int s    = t >> 4;             // k-slice 0..15 (16 cols each)
    const int tile = t & 15;
    const int ti   = tile >> 2;
    const int tj   = tile & 3;

    float acc[4][4];
    #pragma unroll
    for (int a = 0; a < 4; ++a)
        #pragma unroll
        for (int b = 0; b < 4; ++b) acc[a][b] = 0.0f;

    const float* __restrict__ ra = &smem[(4 * ti) * LDW];
    const float* __restrict__ rb = &smem[(4 * tj) * LDW];
    #pragma unroll
    for (int step = 0; step < 4; ++step) {
        const int col = 4 * (s + 16 * step);   // interleaved quads: 2-way max
        float4 av[4];
        #pragma unroll
        for (int r = 0; r < 4; ++r) av[r] = *(const float4*)(ra + r * LDW + col);
        #pragma unroll
        for (int br = 0; br < 4; ++br) {       // one b-row at a time (reg pressure)
            const float4 bv = *(const float4*)(rb + br * LDW + col);
            #pragma unroll
            for (int ar = 0; ar < 4; ++ar) {
                acc[ar][br] = fmaf(av[ar].x, bv.x, acc[ar][br]);
                acc[ar][br] = fmaf(av[ar].y, bv.y, acc[ar][br]);
                acc[ar][br] = fmaf(av[ar].z, bv.z, acc[ar][br]);
                acc[ar][br] = fmaf(av[ar].w, bv.w, acc[ar][br]);
            }
        }
    }

    // Reduce 16 k-slice partials per Gram entry via LDS (conflict-free layout).
    __syncthreads();
    #pragma unroll
    for (int ar = 0; ar < 4; ++ar)
        #pragma unroll
        for (int br = 0; br < 4; ++br)
            smem[(ar * 4 + br) * LDR + t] = acc[ar][br];   // 64 consecutive slots/wave
    __syncthreads();
    {
        const int e  = t >> 4;              // Gram entry 0..15 within 4x4 tile
        const int tt = t & 15;              // which 4x4 tile
        float g = 0.0f;
        #pragma unroll
        for (int ss = 0; ss < 16; ++ss) g += smem[e * LDR + ss * 16 + tt];
        const int i = 4 * (tt >> 2) + (e >> 2);
        const int j = 4 * (tt & 3) + (e & 3);
        ws[(size_t)blk * 256 + i * 16 + j] = g;   // private slot, plain store
    }
}

__launch_bounds__(256, 1)
__global__ void finalize_kernel(const float* __restrict__ ws,
                                float* __restrict__ out) {
    __shared__ float Gs[ROWS][ROWS + 1];
    __shared__ float norms[ROWS];
    __shared__ float contrib[ROWS];

    const int p = blockIdx.x;            // identity
    const int t = threadIdx.x;           // 0..255 = Gram entry i*16+j

    float g = 0.0f;
    #pragma unroll
    for (int c = 0; c < NCHUNK; ++c)
        g += ws[((size_t)(p * NCHUNK + c)) * 256 + t];

    const int i = t >> 4;
    const int j = t & 15;
    Gs[i][j] = g;
    if (i == j) norms[i] = sqrtf(g) + 1e-10f;
    __syncthreads();

    if (t < ROWS) {
        const float ni = norms[t];
        float mf = Gs[t][0] / (ni * norms[0]);
        #pragma unroll
        for (int jj = 1; jj < 8; ++jj) mf = fminf(mf, Gs[t][jj] / (ni * norms[jj]));
        float ms = Gs[t][8] / (ni * norms[8]);
        #pragma unroll
        for (int jj = 9; jj < 16; ++jj) ms = fminf(ms, Gs[t][jj] / (ni * norms[jj]));
        contrib[t] = fmaxf(1.0f - mf, 0.0f) + fmaxf(1.0f - ms, 0.0f);
    }
    __syncthreads();
    if (t == 0) {
        float sum = 0.0f;
        #pragma unroll
        for (int r = 0; r < ROWS; ++r) sum += contrib[r];
        atomicAdd(out, sum);
    }
}

extern "C" void kernel_launch(void* const* d_in, const int* in_sizes, int n_in,
                              void* d_out, int out_size, void* d_ws, size_t ws_size,
                              hipStream_t stream) {
    const float* x = (const float*)d_in[0];
    float* out = (float*)d_out;
    float* ws = (float*)d_ws;            // 2048*256*4 = 2 MB used
    hipMemsetAsync(out, 0, (size_t)out_size * sizeof(float), stream);
    gram_partial_kernel<<<NN / (2 * KK) * NCHUNK, 256, 0, stream>>>(x, ws);
    finalize_kernel<<<NN / (2 * KK), 256, 0, stream>>>(ws, out);
}